// Round 1
// baseline (517.668 us; speedup 1.0000x reference)
//
#include <hip/hip_runtime.h>
#include <math.h>

constexpr int BLK = 256;

// ---------------- CSR build ----------------

__global__ void __launch_bounds__(BLK) hist_kernel(const int* __restrict__ dst,
                                                   int* __restrict__ counts, int e) {
  int i = blockIdx.x * BLK + threadIdx.x;
  if (i < e) atomicAdd(&counts[dst[i]], 1);
}

// block scans 2048 elements (8 per thread); writes inclusive scan into row_ptr[i+1],
// block total into bsum[blockIdx.x]
__global__ void __launch_bounds__(BLK) scan_a(const int* __restrict__ counts,
                                              int* __restrict__ row_ptr,
                                              int* __restrict__ bsum, int n) {
  __shared__ int sd[BLK];
  int i0 = blockIdx.x * 2048 + threadIdx.x * 8;
  int v[8];
  int tsum = 0;
#pragma unroll
  for (int t = 0; t < 8; t++) {
    int idx = i0 + t;
    v[t] = (idx < n) ? counts[idx] : 0;
    tsum += v[t];
  }
  sd[threadIdx.x] = tsum;
  __syncthreads();
  for (int off = 1; off < BLK; off <<= 1) {
    int t = (threadIdx.x >= off) ? sd[threadIdx.x - off] : 0;
    __syncthreads();
    sd[threadIdx.x] += t;
    __syncthreads();
  }
  int run = sd[threadIdx.x] - tsum;  // exclusive prefix of this thread
#pragma unroll
  for (int t = 0; t < 8; t++) {
    run += v[t];
    int idx = i0 + t;
    if (idx < n) row_ptr[idx + 1] = run;  // inclusive
  }
  if (threadIdx.x == BLK - 1) bsum[blockIdx.x] = sd[BLK - 1];
}

// exclusive scan of the (<=256) block sums, in place
__global__ void __launch_bounds__(BLK) scan_b(int* __restrict__ bsum, int nb) {
  __shared__ int sd[BLK];
  int v = (threadIdx.x < nb) ? bsum[threadIdx.x] : 0;
  sd[threadIdx.x] = v;
  __syncthreads();
  for (int off = 1; off < BLK; off <<= 1) {
    int t = (threadIdx.x >= off) ? sd[threadIdx.x - off] : 0;
    __syncthreads();
    sd[threadIdx.x] += t;
    __syncthreads();
  }
  if (threadIdx.x < nb) bsum[threadIdx.x] = sd[threadIdx.x] - v;  // exclusive
}

__global__ void __launch_bounds__(BLK) scan_c(int* __restrict__ row_ptr,
                                              const int* __restrict__ bsum,
                                              const int* __restrict__ counts,
                                              float* __restrict__ dinv, int n) {
  int i = blockIdx.x * BLK + threadIdx.x;
  if (i < n) {
    row_ptr[i + 1] += bsum[i >> 11];
    dinv[i] = rsqrtf((float)counts[i] + 1.0f);
    if (i == 0) row_ptr[0] = 0;
  }
}

__global__ void __launch_bounds__(BLK) fill_kernel(const int* __restrict__ src,
                                                   const int* __restrict__ dst,
                                                   const int* __restrict__ row_ptr,
                                                   int* __restrict__ cursor,
                                                   int* __restrict__ col, int e) {
  int i = blockIdx.x * BLK + threadIdx.x;
  if (i < e) {
    int d = dst[i];
    int pos = atomicAdd(&cursor[d], 1);
    col[row_ptr[d] + pos] = src[i];
  }
}

// ---------------- dense GEMM: G[n][M] = X[n][K] @ W[K][M] ----------------
// block = 256 threads, GROUPS = 256/M column groups, each thread: R rows x 1 col.

template <int K, int M, int R>
__global__ void __launch_bounds__(BLK) gemm_kernel(const float* __restrict__ X,
                                                   const float* __restrict__ W,
                                                   float* __restrict__ G, int n) {
  constexpr int GROUPS = BLK / M;
  constexpr int ROWS = GROUPS * R;
  __shared__ float ws[K][M];
  __shared__ float xs[ROWS][K];
  const int tid = threadIdx.x;

  constexpr int WTOT = K * M;
#pragma unroll
  for (int i = tid * 4; i < WTOT; i += BLK * 4) {
    *(float4*)&((float*)ws)[i] = *(const float4*)&W[i];
  }
  const int row0 = blockIdx.x * ROWS;
  constexpr int XTOT = ROWS * K;
#pragma unroll
  for (int i = tid * 4; i < XTOT; i += BLK * 4) {
    int r = i / K, c = i % K;
    int gr = row0 + r;
    if (gr >= n) gr = n - 1;  // clamp (stores are guarded)
    *(float4*)&xs[r][c] = *(const float4*)&X[(size_t)gr * K + c];
  }
  __syncthreads();

  const int col = tid % M;
  const int grp = tid / M;
  float acc[R];
#pragma unroll
  for (int r = 0; r < R; r++) acc[r] = 0.f;

  for (int k = 0; k < K; k += 4) {
    float w0 = ws[k][col], w1 = ws[k + 1][col], w2 = ws[k + 2][col], w3 = ws[k + 3][col];
#pragma unroll
    for (int r = 0; r < R; r++) {
      float4 xv = *(const float4*)&xs[grp * R + r][k];
      acc[r] += xv.x * w0 + xv.y * w1 + xv.z * w2 + xv.w * w3;
    }
  }

#pragma unroll
  for (int r = 0; r < R; r++) {
    int gr = row0 + grp * R + r;
    if (gr < n) G[(size_t)gr * M + col] = acc[r];
  }
}

// ---------------- aggregation ----------------
// layer 1: 64 channels, one wave per dst node, lane = channel
__global__ void __launch_bounds__(BLK) agg1_kernel(const float* __restrict__ g,
                                                   const int* __restrict__ row_ptr,
                                                   const int* __restrict__ col,
                                                   const float* __restrict__ dinv,
                                                   const float* __restrict__ bias,
                                                   float* __restrict__ out, int n) {
  int node = (blockIdx.x * BLK + threadIdx.x) >> 6;
  int lane = threadIdx.x & 63;
  if (node >= n) return;
  float di = dinv[node];
  float acc = g[(size_t)node * 64 + lane] * di;  // self-loop term
  int beg = row_ptr[node], end = row_ptr[node + 1];
  for (int j = beg; j < end; ++j) {
    int s = col[j];
    acc += g[(size_t)s * 64 + lane] * dinv[s];
  }
  float v = acc * di + bias[lane];
  out[(size_t)node * 64 + lane] = v > 0.f ? v : 0.f;
}

// layer 2: 32 channels; halves of the wave process alternate neighbors
__global__ void __launch_bounds__(BLK) agg2_kernel(const float* __restrict__ g,
                                                   const int* __restrict__ row_ptr,
                                                   const int* __restrict__ col,
                                                   const float* __restrict__ dinv,
                                                   const float* __restrict__ bias,
                                                   float* __restrict__ out, int n) {
  int node = (blockIdx.x * BLK + threadIdx.x) >> 6;
  int lane = threadIdx.x & 63;
  if (node >= n) return;
  int c = lane & 31, half = lane >> 5;
  float di = dinv[node];
  float acc = (half == 0) ? g[(size_t)node * 32 + c] * di : 0.f;
  int beg = row_ptr[node], end = row_ptr[node + 1];
  for (int j = beg + half; j < end; j += 2) {
    int s = col[j];
    acc += g[(size_t)s * 32 + c] * dinv[s];
  }
  acc += __shfl_xor(acc, 32);
  if (half == 0) {
    float v = acc * di + bias[c];
    out[(size_t)node * 32 + c] = v > 0.f ? v : 0.f;
  }
}

// ---------------- launcher ----------------

extern "C" void kernel_launch(void* const* d_in, const int* in_sizes, int n_in,
                              void* d_out, int out_size, void* d_ws, size_t ws_size,
                              hipStream_t stream) {
  const float* x = (const float*)d_in[0];
  const int* ei = (const int*)d_in[1];
  const float* W1 = (const float*)d_in[2];
  const float* b1 = (const float*)d_in[3];
  const float* W2 = (const float*)d_in[4];
  const float* b2 = (const float*)d_in[5];

  const int N = in_sizes[0] / 128;
  const int E = in_sizes[1] / 2;
  const int* src = ei;
  const int* dst = ei + E;

  char* p = (char*)d_ws;
  auto take = [&](size_t bytes) -> char* {
    char* q = p;
    p += (bytes + 255) & ~(size_t)255;
    return q;
  };
  int* counts = (int*)take((size_t)N * 4);
  int* cursor = (int*)take((size_t)N * 4);
  int* row_ptr = (int*)take((size_t)(N + 1) * 4);
  int* bsum = (int*)take(256 * 4);
  int* col = (int*)take((size_t)E * 4);
  float* dinv = (float*)take((size_t)N * 4);
  float* g1 = (float*)take((size_t)N * 64 * 4);
  float* h = (float*)take((size_t)N * 64 * 4);
  float* g2 = (float*)take((size_t)N * 32 * 4);

  hipMemsetAsync(counts, 0, (size_t)N * 4, stream);
  hipMemsetAsync(cursor, 0, (size_t)N * 4, stream);

  const int ge = (E + BLK - 1) / BLK;
  const int gn = (N + BLK - 1) / BLK;
  const int nb = (N + 2047) / 2048;

  hist_kernel<<<ge, BLK, 0, stream>>>(dst, counts, E);
  scan_a<<<nb, BLK, 0, stream>>>(counts, row_ptr, bsum, N);
  scan_b<<<1, BLK, 0, stream>>>(bsum, nb);
  scan_c<<<gn, BLK, 0, stream>>>(row_ptr, bsum, counts, dinv, N);
  fill_kernel<<<ge, BLK, 0, stream>>>(src, dst, row_ptr, cursor, col, E);

  gemm_kernel<128, 64, 8><<<(N + 31) / 32, BLK, 0, stream>>>(x, W1, g1, N);
  agg1_kernel<<<(N + 3) / 4, BLK, 0, stream>>>(g1, row_ptr, col, dinv, b1, h, N);
  gemm_kernel<64, 32, 8><<<(N + 63) / 64, BLK, 0, stream>>>(h, W2, g2, N);
  agg2_kernel<<<(N + 3) / 4, BLK, 0, stream>>>(g2, row_ptr, col, dinv, b2, (float*)d_out, N);
}

// Round 2
// 425.770 us; speedup vs baseline: 1.2158x; 1.2158x over previous
//
#include <hip/hip_runtime.h>
#include <math.h>

constexpr int BLK = 256;

// ---------------- CSR build ----------------

__global__ void __launch_bounds__(BLK) hist_kernel(const int* __restrict__ dst,
                                                   int* __restrict__ counts, int e) {
  int i = blockIdx.x * BLK + threadIdx.x;
  if (i < e) atomicAdd(&counts[dst[i]], 1);
}

// block scans 2048 elements (8 per thread); writes inclusive scan into row_ptr[i+1],
// block total into bsum[blockIdx.x]
__global__ void __launch_bounds__(BLK) scan_a(const int* __restrict__ counts,
                                              int* __restrict__ row_ptr,
                                              int* __restrict__ bsum, int n) {
  __shared__ int sd[BLK];
  int i0 = blockIdx.x * 2048 + threadIdx.x * 8;
  int v[8];
  int tsum = 0;
#pragma unroll
  for (int t = 0; t < 8; t++) {
    int idx = i0 + t;
    v[t] = (idx < n) ? counts[idx] : 0;
    tsum += v[t];
  }
  sd[threadIdx.x] = tsum;
  __syncthreads();
  for (int off = 1; off < BLK; off <<= 1) {
    int t = (threadIdx.x >= off) ? sd[threadIdx.x - off] : 0;
    __syncthreads();
    sd[threadIdx.x] += t;
    __syncthreads();
  }
  int run = sd[threadIdx.x] - tsum;  // exclusive prefix of this thread
#pragma unroll
  for (int t = 0; t < 8; t++) {
    run += v[t];
    int idx = i0 + t;
    if (idx < n) row_ptr[idx + 1] = run;  // inclusive
  }
  if (threadIdx.x == BLK - 1) bsum[blockIdx.x] = sd[BLK - 1];
}

// exclusive scan of the (<=256) block sums, in place
__global__ void __launch_bounds__(BLK) scan_b(int* __restrict__ bsum, int nb) {
  __shared__ int sd[BLK];
  int v = (threadIdx.x < nb) ? bsum[threadIdx.x] : 0;
  sd[threadIdx.x] = v;
  __syncthreads();
  for (int off = 1; off < BLK; off <<= 1) {
    int t = (threadIdx.x >= off) ? sd[threadIdx.x - off] : 0;
    __syncthreads();
    sd[threadIdx.x] += t;
    __syncthreads();
  }
  if (threadIdx.x < nb) bsum[threadIdx.x] = sd[threadIdx.x] - v;  // exclusive
}

// finalize row_ptr, compute dinv, and init cursor[i] = exclusive start of row i
__global__ void __launch_bounds__(BLK) scan_c(int* __restrict__ row_ptr,
                                              const int* __restrict__ bsum,
                                              const int* __restrict__ counts,
                                              float* __restrict__ dinv,
                                              int* __restrict__ cursor, int n) {
  int i = blockIdx.x * BLK + threadIdx.x;
  if (i < n) {
    int inc = row_ptr[i + 1] + bsum[i >> 11];
    row_ptr[i + 1] = inc;
    cursor[i] = inc - counts[i];
    dinv[i] = rsqrtf((float)counts[i] + 1.0f);
    if (i == 0) row_ptr[0] = 0;
  }
}

__global__ void __launch_bounds__(BLK) fill_kernel(const int* __restrict__ src,
                                                   const int* __restrict__ dst,
                                                   int* __restrict__ cursor,
                                                   int* __restrict__ col, int e) {
  int i = blockIdx.x * BLK + threadIdx.x;
  if (i < e) {
    int pos = atomicAdd(&cursor[dst[i]], 1);
    col[pos] = src[i];
  }
}

// ---------------- dense GEMM: G[n][M] = (X[n][K] @ W[K][M]) * dinv[n] ----------------
// block = 256 threads, GROUPS = 256/M column groups, each thread: R rows x 1 col.

template <int K, int M, int R>
__global__ void __launch_bounds__(BLK) gemm_kernel(const float* __restrict__ X,
                                                   const float* __restrict__ W,
                                                   const float* __restrict__ dinv,
                                                   float* __restrict__ G, int n) {
  constexpr int GROUPS = BLK / M;
  constexpr int ROWS = GROUPS * R;
  __shared__ float ws[K][M];
  __shared__ float xs[ROWS][K];
  const int tid = threadIdx.x;

  constexpr int WTOT = K * M;
#pragma unroll
  for (int i = tid * 4; i < WTOT; i += BLK * 4) {
    *(float4*)&((float*)ws)[i] = *(const float4*)&W[i];
  }
  const int row0 = blockIdx.x * ROWS;
  constexpr int XTOT = ROWS * K;
#pragma unroll
  for (int i = tid * 4; i < XTOT; i += BLK * 4) {
    int r = i / K, c = i % K;
    int gr = row0 + r;
    if (gr >= n) gr = n - 1;  // clamp (stores are guarded)
    *(float4*)&xs[r][c] = *(const float4*)&X[(size_t)gr * K + c];
  }
  __syncthreads();

  const int col = tid % M;
  const int grp = tid / M;
  float acc[R];
#pragma unroll
  for (int r = 0; r < R; r++) acc[r] = 0.f;

  for (int k = 0; k < K; k += 4) {
    float w0 = ws[k][col], w1 = ws[k + 1][col], w2 = ws[k + 2][col], w3 = ws[k + 3][col];
#pragma unroll
    for (int r = 0; r < R; r++) {
      float4 xv = *(const float4*)&xs[grp * R + r][k];
      acc[r] += xv.x * w0 + xv.y * w1 + xv.z * w2 + xv.w * w3;
    }
  }

#pragma unroll
  for (int r = 0; r < R; r++) {
    int gr = row0 + grp * R + r;
    if (gr < n) G[(size_t)gr * M + col] = acc[r] * dinv[gr];
  }
}

// ---------------- aggregation ----------------
// gs already holds (X@W)*dinv[row]. out[i] = relu(dinv[i]*(gs[i] + sum_s gs[s]) + b)

// layer 1: 64 channels, one wave per dst node, lane = channel; 8-deep MLP unroll
__global__ void __launch_bounds__(BLK) agg1_kernel(const float* __restrict__ gs,
                                                   const int* __restrict__ row_ptr,
                                                   const int* __restrict__ col,
                                                   const float* __restrict__ dinv,
                                                   const float* __restrict__ bias,
                                                   float* __restrict__ out, int n) {
  int node = (blockIdx.x * BLK + threadIdx.x) >> 6;
  int lane = threadIdx.x & 63;
  if (node >= n) return;
  int beg = row_ptr[node], end = row_ptr[node + 1];
  float acc = gs[(size_t)node * 64 + lane];  // self-loop term (prescaled)
  int j = beg;
  for (; j + 8 <= end; j += 8) {
    int s0 = col[j + 0], s1 = col[j + 1], s2 = col[j + 2], s3 = col[j + 3];
    int s4 = col[j + 4], s5 = col[j + 5], s6 = col[j + 6], s7 = col[j + 7];
    float a0 = gs[(size_t)s0 * 64 + lane];
    float a1 = gs[(size_t)s1 * 64 + lane];
    float a2 = gs[(size_t)s2 * 64 + lane];
    float a3 = gs[(size_t)s3 * 64 + lane];
    float a4 = gs[(size_t)s4 * 64 + lane];
    float a5 = gs[(size_t)s5 * 64 + lane];
    float a6 = gs[(size_t)s6 * 64 + lane];
    float a7 = gs[(size_t)s7 * 64 + lane];
    acc += ((a0 + a1) + (a2 + a3)) + ((a4 + a5) + (a6 + a7));
  }
  for (; j < end; ++j) acc += gs[(size_t)col[j] * 64 + lane];
  float v = acc * dinv[node] + bias[lane];
  out[(size_t)node * 64 + lane] = v > 0.f ? v : 0.f;
}

// layer 2: 32 channels; halves of the wave process alternate neighbors, 4-deep unroll
__global__ void __launch_bounds__(BLK) agg2_kernel(const float* __restrict__ gs,
                                                   const int* __restrict__ row_ptr,
                                                   const int* __restrict__ col,
                                                   const float* __restrict__ dinv,
                                                   const float* __restrict__ bias,
                                                   float* __restrict__ out, int n) {
  int node = (blockIdx.x * BLK + threadIdx.x) >> 6;
  int lane = threadIdx.x & 63;
  if (node >= n) return;
  int c = lane & 31, half = lane >> 5;
  float acc = (half == 0) ? gs[(size_t)node * 32 + c] : 0.f;
  int beg = row_ptr[node], end = row_ptr[node + 1];
  int j = beg + half;
  // each half-wave strides by 2; unroll 4 => 8 edges in flight per wave
  for (; j + 6 < end; j += 8) {
    int s0 = col[j + 0], s1 = col[j + 2], s2 = col[j + 4], s3 = col[j + 6];
    float a0 = gs[(size_t)s0 * 32 + c];
    float a1 = gs[(size_t)s1 * 32 + c];
    float a2 = gs[(size_t)s2 * 32 + c];
    float a3 = gs[(size_t)s3 * 32 + c];
    acc += (a0 + a1) + (a2 + a3);
  }
  for (; j < end; j += 2) acc += gs[(size_t)col[j] * 32 + c];
  acc += __shfl_xor(acc, 32);
  if (half == 0) {
    float v = acc * dinv[node] + bias[c];
    out[(size_t)node * 32 + c] = v > 0.f ? v : 0.f;
  }
}

// ---------------- launcher ----------------

extern "C" void kernel_launch(void* const* d_in, const int* in_sizes, int n_in,
                              void* d_out, int out_size, void* d_ws, size_t ws_size,
                              hipStream_t stream) {
  const float* x = (const float*)d_in[0];
  const int* ei = (const int*)d_in[1];
  const float* W1 = (const float*)d_in[2];
  const float* b1 = (const float*)d_in[3];
  const float* W2 = (const float*)d_in[4];
  const float* b2 = (const float*)d_in[5];

  const int N = in_sizes[0] / 128;
  const int E = in_sizes[1] / 2;
  const int* src = ei;
  const int* dst = ei + E;

  char* p = (char*)d_ws;
  auto take = [&](size_t bytes) -> char* {
    char* q = p;
    p += (bytes + 255) & ~(size_t)255;
    return q;
  };
  int* counts = (int*)take((size_t)N * 4);
  int* cursor = (int*)take((size_t)N * 4);
  int* row_ptr = (int*)take((size_t)(N + 1) * 4);
  int* bsum = (int*)take(256 * 4);
  int* col = (int*)take((size_t)E * 4);
  float* dinv = (float*)take((size_t)N * 4);
  float* g1 = (float*)take((size_t)N * 64 * 4);
  float* h = (float*)take((size_t)N * 64 * 4);
  float* g2 = (float*)take((size_t)N * 32 * 4);

  hipMemsetAsync(counts, 0, (size_t)N * 4, stream);

  const int ge = (E + BLK - 1) / BLK;
  const int gn = (N + BLK - 1) / BLK;
  const int nb = (N + 2047) / 2048;

  hist_kernel<<<ge, BLK, 0, stream>>>(dst, counts, E);
  scan_a<<<nb, BLK, 0, stream>>>(counts, row_ptr, bsum, N);
  scan_b<<<1, BLK, 0, stream>>>(bsum, nb);
  scan_c<<<gn, BLK, 0, stream>>>(row_ptr, bsum, counts, dinv, cursor, N);
  fill_kernel<<<ge, BLK, 0, stream>>>(src, dst, cursor, col, E);

  gemm_kernel<128, 64, 8><<<(N + 31) / 32, BLK, 0, stream>>>(x, W1, dinv, g1, N);
  agg1_kernel<<<(N + 3) / 4, BLK, 0, stream>>>(g1, row_ptr, col, dinv, b1, h, N);
  gemm_kernel<64, 32, 8><<<(N + 63) / 64, BLK, 0, stream>>>(h, W2, dinv, g2, N);
  agg2_kernel<<<(N + 3) / 4, BLK, 0, stream>>>(g2, row_ptr, col, dinv, b2, (float*)d_out, N);
}

// Round 3
// 371.850 us; speedup vs baseline: 1.3921x; 1.1450x over previous
//
#include <hip/hip_runtime.h>
#include <math.h>

constexpr int BLK = 256;
constexpr int NSLICE = 8;   // one slice per XCD (blockIdx & 7 round-robin heuristic)
constexpr int EPT = 8;      // edges per thread
constexpr int EPB = BLK * EPT;

// ---------------- CSR build (XCD-sliced counting sort) ----------------
// Each slice owns dst in [slice*span, slice*span+span); every slice streams the
// whole edge list (coalesced) and filters, so atomics + scatters stay in one
// XCD's L2 window (~50KB counts / ~800KB col per slice).

__global__ void __launch_bounds__(BLK) hist_sliced(const int* __restrict__ dst,
                                                   int* __restrict__ counts,
                                                   int e, int span) {
  const int slice = blockIdx.x & (NSLICE - 1);
  const int chunk = blockIdx.x / NSLICE;
  const unsigned lo = (unsigned)(slice * span);
  const int i0 = chunk * EPB + threadIdx.x * EPT;
  if (i0 + EPT <= e) {
    int4 a = *(const int4*)&dst[i0];
    int4 b = *(const int4*)&dst[i0 + 4];
    int d[8] = {a.x, a.y, a.z, a.w, b.x, b.y, b.z, b.w};
#pragma unroll
    for (int t = 0; t < 8; t++)
      if ((unsigned)(d[t] - lo) < (unsigned)span) atomicAdd(&counts[d[t]], 1);
  } else {
    int iend = e < i0 + EPT ? e : i0 + EPT;
    for (int i = i0; i < iend; i++) {
      int d = dst[i];
      if ((unsigned)(d - lo) < (unsigned)span) atomicAdd(&counts[d], 1);
    }
  }
}

__global__ void __launch_bounds__(BLK) fill_sliced(const int* __restrict__ src,
                                                   const int* __restrict__ dst,
                                                   int* __restrict__ cursor,
                                                   int* __restrict__ col,
                                                   int e, int span) {
  const int slice = blockIdx.x & (NSLICE - 1);
  const int chunk = blockIdx.x / NSLICE;
  const unsigned lo = (unsigned)(slice * span);
  const int i0 = chunk * EPB + threadIdx.x * EPT;
  if (i0 + EPT <= e) {
    int4 da = *(const int4*)&dst[i0];
    int4 db = *(const int4*)&dst[i0 + 4];
    int4 sa = *(const int4*)&src[i0];
    int4 sb = *(const int4*)&src[i0 + 4];
    int d[8] = {da.x, da.y, da.z, da.w, db.x, db.y, db.z, db.w};
    int s[8] = {sa.x, sa.y, sa.z, sa.w, sb.x, sb.y, sb.z, sb.w};
#pragma unroll
    for (int t = 0; t < 8; t++)
      if ((unsigned)(d[t] - lo) < (unsigned)span) {
        int pos = atomicAdd(&cursor[d[t]], 1);
        col[pos] = s[t];
      }
  } else {
    int iend = e < i0 + EPT ? e : i0 + EPT;
    for (int i = i0; i < iend; i++) {
      int d = dst[i];
      if ((unsigned)(d - lo) < (unsigned)span) {
        int pos = atomicAdd(&cursor[d], 1);
        col[pos] = src[i];
      }
    }
  }
}

// block scans 2048 elements (8 per thread); writes inclusive scan into row_ptr[i+1],
// block total into bsum[blockIdx.x]
__global__ void __launch_bounds__(BLK) scan_a(const int* __restrict__ counts,
                                              int* __restrict__ row_ptr,
                                              int* __restrict__ bsum, int n) {
  __shared__ int sd[BLK];
  int i0 = blockIdx.x * 2048 + threadIdx.x * 8;
  int v[8];
  int tsum = 0;
#pragma unroll
  for (int t = 0; t < 8; t++) {
    int idx = i0 + t;
    v[t] = (idx < n) ? counts[idx] : 0;
    tsum += v[t];
  }
  sd[threadIdx.x] = tsum;
  __syncthreads();
  for (int off = 1; off < BLK; off <<= 1) {
    int t = (threadIdx.x >= off) ? sd[threadIdx.x - off] : 0;
    __syncthreads();
    sd[threadIdx.x] += t;
    __syncthreads();
  }
  int run = sd[threadIdx.x] - tsum;  // exclusive prefix of this thread
#pragma unroll
  for (int t = 0; t < 8; t++) {
    run += v[t];
    int idx = i0 + t;
    if (idx < n) row_ptr[idx + 1] = run;  // inclusive
  }
  if (threadIdx.x == BLK - 1) bsum[blockIdx.x] = sd[BLK - 1];
}

// exclusive scan of the (<=256) block sums, in place
__global__ void __launch_bounds__(BLK) scan_b(int* __restrict__ bsum, int nb) {
  __shared__ int sd[BLK];
  int v = (threadIdx.x < nb) ? bsum[threadIdx.x] : 0;
  sd[threadIdx.x] = v;
  __syncthreads();
  for (int off = 1; off < BLK; off <<= 1) {
    int t = (threadIdx.x >= off) ? sd[threadIdx.x - off] : 0;
    __syncthreads();
    sd[threadIdx.x] += t;
    __syncthreads();
  }
  if (threadIdx.x < nb) bsum[threadIdx.x] = sd[threadIdx.x] - v;  // exclusive
}

// finalize row_ptr, compute dinv, and init cursor[i] = exclusive start of row i
__global__ void __launch_bounds__(BLK) scan_c(int* __restrict__ row_ptr,
                                              const int* __restrict__ bsum,
                                              const int* __restrict__ counts,
                                              float* __restrict__ dinv,
                                              int* __restrict__ cursor, int n) {
  int i = blockIdx.x * BLK + threadIdx.x;
  if (i < n) {
    int inc = row_ptr[i + 1] + bsum[i >> 11];
    row_ptr[i + 1] = inc;
    cursor[i] = inc - counts[i];
    dinv[i] = rsqrtf((float)counts[i] + 1.0f);
    if (i == 0) row_ptr[0] = 0;
  }
}

// ---------------- dense GEMM: G[n][M] = (X[n][K] @ W[K][M]) * dinv[n] ----------------

template <int K, int M, int R>
__global__ void __launch_bounds__(BLK) gemm_kernel(const float* __restrict__ X,
                                                   const float* __restrict__ W,
                                                   const float* __restrict__ dinv,
                                                   float* __restrict__ G, int n) {
  constexpr int GROUPS = BLK / M;
  constexpr int ROWS = GROUPS * R;
  __shared__ float ws[K][M];
  __shared__ float xs[ROWS][K];
  const int tid = threadIdx.x;

  constexpr int WTOT = K * M;
#pragma unroll
  for (int i = tid * 4; i < WTOT; i += BLK * 4) {
    *(float4*)&((float*)ws)[i] = *(const float4*)&W[i];
  }
  const int row0 = blockIdx.x * ROWS;
  constexpr int XTOT = ROWS * K;
#pragma unroll
  for (int i = tid * 4; i < XTOT; i += BLK * 4) {
    int r = i / K, c = i % K;
    int gr = row0 + r;
    if (gr >= n) gr = n - 1;  // clamp (stores are guarded)
    *(float4*)&xs[r][c] = *(const float4*)&X[(size_t)gr * K + c];
  }
  __syncthreads();

  const int col = tid % M;
  const int grp = tid / M;
  float acc[R];
#pragma unroll
  for (int r = 0; r < R; r++) acc[r] = 0.f;

  for (int k = 0; k < K; k += 4) {
    float w0 = ws[k][col], w1 = ws[k + 1][col], w2 = ws[k + 2][col], w3 = ws[k + 3][col];
#pragma unroll
    for (int r = 0; r < R; r++) {
      float4 xv = *(const float4*)&xs[grp * R + r][k];
      acc[r] += xv.x * w0 + xv.y * w1 + xv.z * w2 + xv.w * w3;
    }
  }

#pragma unroll
  for (int r = 0; r < R; r++) {
    int gr = row0 + grp * R + r;
    if (gr < n) G[(size_t)gr * M + col] = acc[r] * dinv[gr];
  }
}

// ---------------- aggregation ----------------
// gs already holds (X@W)*dinv[row]. out[i] = relu(dinv[i]*(gs[i] + sum_s gs[s]) + b)

__global__ void __launch_bounds__(BLK) agg1_kernel(const float* __restrict__ gs,
                                                   const int* __restrict__ row_ptr,
                                                   const int* __restrict__ col,
                                                   const float* __restrict__ dinv,
                                                   const float* __restrict__ bias,
                                                   float* __restrict__ out, int n) {
  int node = (blockIdx.x * BLK + threadIdx.x) >> 6;
  int lane = threadIdx.x & 63;
  if (node >= n) return;
  int beg = row_ptr[node], end = row_ptr[node + 1];
  float acc = gs[(size_t)node * 64 + lane];  // self-loop term (prescaled)
  int j = beg;
  for (; j + 8 <= end; j += 8) {
    int s0 = col[j + 0], s1 = col[j + 1], s2 = col[j + 2], s3 = col[j + 3];
    int s4 = col[j + 4], s5 = col[j + 5], s6 = col[j + 6], s7 = col[j + 7];
    float a0 = gs[(size_t)s0 * 64 + lane];
    float a1 = gs[(size_t)s1 * 64 + lane];
    float a2 = gs[(size_t)s2 * 64 + lane];
    float a3 = gs[(size_t)s3 * 64 + lane];
    float a4 = gs[(size_t)s4 * 64 + lane];
    float a5 = gs[(size_t)s5 * 64 + lane];
    float a6 = gs[(size_t)s6 * 64 + lane];
    float a7 = gs[(size_t)s7 * 64 + lane];
    acc += ((a0 + a1) + (a2 + a3)) + ((a4 + a5) + (a6 + a7));
  }
  for (; j < end; ++j) acc += gs[(size_t)col[j] * 64 + lane];
  float v = acc * dinv[node] + bias[lane];
  out[(size_t)node * 64 + lane] = v > 0.f ? v : 0.f;
}

__global__ void __launch_bounds__(BLK) agg2_kernel(const float* __restrict__ gs,
                                                   const int* __restrict__ row_ptr,
                                                   const int* __restrict__ col,
                                                   const float* __restrict__ dinv,
                                                   const float* __restrict__ bias,
                                                   float* __restrict__ out, int n) {
  int node = (blockIdx.x * BLK + threadIdx.x) >> 6;
  int lane = threadIdx.x & 63;
  if (node >= n) return;
  int c = lane & 31, half = lane >> 5;
  float acc = (half == 0) ? gs[(size_t)node * 32 + c] : 0.f;
  int beg = row_ptr[node], end = row_ptr[node + 1];
  int j = beg + half;
  for (; j + 6 < end; j += 8) {
    int s0 = col[j + 0], s1 = col[j + 2], s2 = col[j + 4], s3 = col[j + 6];
    float a0 = gs[(size_t)s0 * 32 + c];
    float a1 = gs[(size_t)s1 * 32 + c];
    float a2 = gs[(size_t)s2 * 32 + c];
    float a3 = gs[(size_t)s3 * 32 + c];
    acc += (a0 + a1) + (a2 + a3);
  }
  for (; j < end; j += 2) acc += gs[(size_t)col[j] * 32 + c];
  acc += __shfl_xor(acc, 32);
  if (half == 0) {
    float v = acc * dinv[node] + bias[c];
    out[(size_t)node * 32 + c] = v > 0.f ? v : 0.f;
  }
}

// ---------------- launcher ----------------

extern "C" void kernel_launch(void* const* d_in, const int* in_sizes, int n_in,
                              void* d_out, int out_size, void* d_ws, size_t ws_size,
                              hipStream_t stream) {
  const float* x = (const float*)d_in[0];
  const int* ei = (const int*)d_in[1];
  const float* W1 = (const float*)d_in[2];
  const float* b1 = (const float*)d_in[3];
  const float* W2 = (const float*)d_in[4];
  const float* b2 = (const float*)d_in[5];

  const int N = in_sizes[0] / 128;
  const int E = in_sizes[1] / 2;
  const int* src = ei;
  const int* dst = ei + E;

  char* p = (char*)d_ws;
  auto take = [&](size_t bytes) -> char* {
    char* q = p;
    p += (bytes + 255) & ~(size_t)255;
    return q;
  };
  int* counts = (int*)take((size_t)N * 4);
  int* cursor = (int*)take((size_t)N * 4);
  int* row_ptr = (int*)take((size_t)(N + 1) * 4);
  int* bsum = (int*)take(256 * 4);
  int* col = (int*)take((size_t)E * 4);
  float* dinv = (float*)take((size_t)N * 4);
  float* g1 = (float*)take((size_t)N * 64 * 4);
  float* h = (float*)take((size_t)N * 64 * 4);
  float* g2 = (float*)take((size_t)N * 32 * 4);

  hipMemsetAsync(counts, 0, (size_t)N * 4, stream);

  const int gn = (N + BLK - 1) / BLK;
  const int nb = (N + 2047) / 2048;
  const int span = (N + NSLICE - 1) / NSLICE;
  const int nchunk = (E + EPB - 1) / EPB;
  const int gsliced = nchunk * NSLICE;

  hist_sliced<<<gsliced, BLK, 0, stream>>>(dst, counts, E, span);
  scan_a<<<nb, BLK, 0, stream>>>(counts, row_ptr, bsum, N);
  scan_b<<<1, BLK, 0, stream>>>(bsum, nb);
  scan_c<<<gn, BLK, 0, stream>>>(row_ptr, bsum, counts, dinv, cursor, N);
  fill_sliced<<<gsliced, BLK, 0, stream>>>(src, dst, cursor, col, E, span);

  gemm_kernel<128, 64, 8><<<(N + 31) / 32, BLK, 0, stream>>>(x, W1, dinv, g1, N);
  agg1_kernel<<<(N + 3) / 4, BLK, 0, stream>>>(g1, row_ptr, col, dinv, b1, h, N);
  gemm_kernel<64, 32, 8><<<(N + 63) / 64, BLK, 0, stream>>>(h, W2, dinv, g2, N);
  agg2_kernel<<<(N + 3) / 4, BLK, 0, stream>>>(g2, row_ptr, col, dinv, b2, (float*)d_out, N);
}

// Round 4
// 268.628 us; speedup vs baseline: 1.9271x; 1.3843x over previous
//
#include <hip/hip_runtime.h>
#include <math.h>

constexpr int BLK = 256;
constexpr int NB_MAX = 256;      // max coarse buckets (supports N <= 131072)
constexpr int BSHIFT = 9;        // 512 nodes per bucket
constexpr int BSPAN = 1 << BSHIFT;
constexpr int CAP = 10240;       // per-bucket bin capacity (mean 8192 @ E=1.6M, +22 sigma)
constexpr int EPT2 = 16;         // edges per thread in binpass
constexpr int EPBB = BLK * EPT2; // 4096 edges per block

// ---------------- pass 1: coarse binning into block-private chunks ----------------
__global__ void __launch_bounds__(BLK) binpass(const int* __restrict__ src,
                                               const int* __restrict__ dst,
                                               int e, int* __restrict__ bins,
                                               int* __restrict__ tail) {
  __shared__ int lcnt[NB_MAX], gbase[NB_MAX], lcur[NB_MAX];
  const int tid = threadIdx.x;
  lcnt[tid] = 0;
  lcur[tid] = 0;
  __syncthreads();
  const int i0 = blockIdx.x * EPBB;
  int bb[EPT2], pk[EPT2];
#pragma unroll
  for (int k = 0; k < EPT2; k++) {
    int i = i0 + k * BLK + tid;
    if (i < e) {
      int d = dst[i], s = src[i];
      bb[k] = d >> BSHIFT;
      pk[k] = ((d & (BSPAN - 1)) << 23) | s;   // src < 2^23, dlo < 2^9
      atomicAdd(&lcnt[bb[k]], 1);
    } else {
      bb[k] = -1;
    }
  }
  __syncthreads();
  gbase[tid] = atomicAdd(&tail[tid], lcnt[tid]);  // reserve contiguous chunk per bucket
  __syncthreads();
#pragma unroll
  for (int k = 0; k < EPT2; k++) {
    if (bb[k] >= 0) {
      int idx = atomicAdd(&lcur[bb[k]], 1);
      bins[bb[k] * CAP + gbase[bb[k]] + idx] = pk[k];
    }
  }
}

// ---------------- pass 2: exclusive scan of bucket totals ----------------
__global__ void __launch_bounds__(BLK) scan256(const int* __restrict__ tail,
                                               int* __restrict__ bbase,
                                               int* __restrict__ row_ptr,
                                               int n, int e) {
  __shared__ int sd[BLK];
  int v = tail[threadIdx.x];
  sd[threadIdx.x] = v;
  __syncthreads();
  for (int off = 1; off < BLK; off <<= 1) {
    int t = (threadIdx.x >= off) ? sd[threadIdx.x - off] : 0;
    __syncthreads();
    sd[threadIdx.x] += t;
    __syncthreads();
  }
  bbase[threadIdx.x] = sd[threadIdx.x] - v;
  if (threadIdx.x == 0) row_ptr[n] = e;
}

// ---------------- pass 3: per-bucket counting sort (block-private col region) ----------------
__global__ void __launch_bounds__(BLK) bucket_sort(const int* __restrict__ bins,
                                                   const int* __restrict__ tail,
                                                   const int* __restrict__ bbase,
                                                   int* __restrict__ row_ptr,
                                                   int* __restrict__ col,
                                                   float* __restrict__ dinv, int n) {
  __shared__ int hist[BSPAN], lpre[BSPAN], lcur[BSPAN], sd[BLK];
  const int b = blockIdx.x, tid = threadIdx.x;
  const int cnt = tail[b];
  const int base = bbase[b];
  const int node0 = b << BSHIFT;
  const int nNodes = min(BSPAN, n - node0);
  const int* bin = bins + (size_t)b * CAP;

  hist[tid] = 0; hist[tid + BLK] = 0;
  lcur[tid] = 0; lcur[tid + BLK] = 0;
  __syncthreads();
  for (int j = tid; j < cnt; j += BLK) atomicAdd(&hist[(unsigned)bin[j] >> 23], 1);
  __syncthreads();
  // exclusive scan over 512 counters (2 per thread)
  int v0 = hist[2 * tid], v1 = hist[2 * tid + 1], ts = v0 + v1;
  sd[tid] = ts;
  __syncthreads();
  for (int off = 1; off < BLK; off <<= 1) {
    int t = (tid >= off) ? sd[tid - off] : 0;
    __syncthreads();
    sd[tid] += t;
    __syncthreads();
  }
  int ex = sd[tid] - ts;
  lpre[2 * tid] = ex;
  lpre[2 * tid + 1] = ex + v0;
  __syncthreads();
  for (int d = tid; d < nNodes; d += BLK) {
    row_ptr[node0 + d] = base + lpre[d];
    dinv[node0 + d] = rsqrtf((float)hist[d] + 1.0f);
  }
  for (int j = tid; j < cnt; j += BLK) {
    int pkv = bin[j];
    int dlo = (unsigned)pkv >> 23;
    int idx = atomicAdd(&lcur[dlo], 1);
    col[base + lpre[dlo] + idx] = pkv & 0x7FFFFF;
  }
}

// ---------------- dense GEMM: G[n][M] = (X[n][K] @ W[K][M]) * dinv[n] ----------------
template <int K, int M, int R>
__global__ void __launch_bounds__(BLK) gemm_kernel(const float* __restrict__ X,
                                                   const float* __restrict__ W,
                                                   const float* __restrict__ dinv,
                                                   float* __restrict__ G, int n) {
  constexpr int GROUPS = BLK / M;
  constexpr int ROWS = GROUPS * R;
  __shared__ float ws[K][M];
  __shared__ float xs[ROWS][K];
  const int tid = threadIdx.x;

  constexpr int WTOT = K * M;
#pragma unroll
  for (int i = tid * 4; i < WTOT; i += BLK * 4) {
    *(float4*)&((float*)ws)[i] = *(const float4*)&W[i];
  }
  const int row0 = blockIdx.x * ROWS;
  constexpr int XTOT = ROWS * K;
#pragma unroll
  for (int i = tid * 4; i < XTOT; i += BLK * 4) {
    int r = i / K, c = i % K;
    int gr = row0 + r;
    if (gr >= n) gr = n - 1;  // clamp (stores are guarded)
    *(float4*)&xs[r][c] = *(const float4*)&X[(size_t)gr * K + c];
  }
  __syncthreads();

  const int col = tid % M;
  const int grp = tid / M;
  float acc[R];
#pragma unroll
  for (int r = 0; r < R; r++) acc[r] = 0.f;

  for (int k = 0; k < K; k += 4) {
    float w0 = ws[k][col], w1 = ws[k + 1][col], w2 = ws[k + 2][col], w3 = ws[k + 3][col];
#pragma unroll
    for (int r = 0; r < R; r++) {
      float4 xv = *(const float4*)&xs[grp * R + r][k];
      acc[r] += xv.x * w0 + xv.y * w1 + xv.z * w2 + xv.w * w3;
    }
  }

#pragma unroll
  for (int r = 0; r < R; r++) {
    int gr = row0 + grp * R + r;
    if (gr < n) G[(size_t)gr * M + col] = acc[r] * dinv[gr];
  }
}

// ---------------- aggregation ----------------
// gs already holds (X@W)*dinv[row]. out[i] = relu(dinv[i]*(gs[i] + sum_s gs[s]) + b)

__global__ void __launch_bounds__(BLK) agg1_kernel(const float* __restrict__ gs,
                                                   const int* __restrict__ row_ptr,
                                                   const int* __restrict__ col,
                                                   const float* __restrict__ dinv,
                                                   const float* __restrict__ bias,
                                                   float* __restrict__ out, int n) {
  int node = (blockIdx.x * BLK + threadIdx.x) >> 6;
  int lane = threadIdx.x & 63;
  if (node >= n) return;
  int beg = row_ptr[node], end = row_ptr[node + 1];
  float acc = gs[(size_t)node * 64 + lane];  // self-loop term (prescaled)
  int j = beg;
  for (; j + 8 <= end; j += 8) {
    int s0 = col[j + 0], s1 = col[j + 1], s2 = col[j + 2], s3 = col[j + 3];
    int s4 = col[j + 4], s5 = col[j + 5], s6 = col[j + 6], s7 = col[j + 7];
    float a0 = gs[(size_t)s0 * 64 + lane];
    float a1 = gs[(size_t)s1 * 64 + lane];
    float a2 = gs[(size_t)s2 * 64 + lane];
    float a3 = gs[(size_t)s3 * 64 + lane];
    float a4 = gs[(size_t)s4 * 64 + lane];
    float a5 = gs[(size_t)s5 * 64 + lane];
    float a6 = gs[(size_t)s6 * 64 + lane];
    float a7 = gs[(size_t)s7 * 64 + lane];
    acc += ((a0 + a1) + (a2 + a3)) + ((a4 + a5) + (a6 + a7));
  }
  for (; j < end; ++j) acc += gs[(size_t)col[j] * 64 + lane];
  float v = acc * dinv[node] + bias[lane];
  out[(size_t)node * 64 + lane] = v > 0.f ? v : 0.f;
}

__global__ void __launch_bounds__(BLK) agg2_kernel(const float* __restrict__ gs,
                                                   const int* __restrict__ row_ptr,
                                                   const int* __restrict__ col,
                                                   const float* __restrict__ dinv,
                                                   const float* __restrict__ bias,
                                                   float* __restrict__ out, int n) {
  int node = (blockIdx.x * BLK + threadIdx.x) >> 6;
  int lane = threadIdx.x & 63;
  if (node >= n) return;
  int c = lane & 31, half = lane >> 5;
  float acc = (half == 0) ? gs[(size_t)node * 32 + c] : 0.f;
  int beg = row_ptr[node], end = row_ptr[node + 1];
  int j = beg + half;
  for (; j + 6 < end; j += 8) {
    int s0 = col[j + 0], s1 = col[j + 2], s2 = col[j + 4], s3 = col[j + 6];
    float a0 = gs[(size_t)s0 * 32 + c];
    float a1 = gs[(size_t)s1 * 32 + c];
    float a2 = gs[(size_t)s2 * 32 + c];
    float a3 = gs[(size_t)s3 * 32 + c];
    acc += (a0 + a1) + (a2 + a3);
  }
  for (; j < end; j += 2) acc += gs[(size_t)col[j] * 32 + c];
  acc += __shfl_xor(acc, 32);
  if (half == 0) {
    float v = acc * dinv[node] + bias[c];
    out[(size_t)node * 32 + c] = v > 0.f ? v : 0.f;
  }
}

// ---------------- launcher ----------------

extern "C" void kernel_launch(void* const* d_in, const int* in_sizes, int n_in,
                              void* d_out, int out_size, void* d_ws, size_t ws_size,
                              hipStream_t stream) {
  const float* x = (const float*)d_in[0];
  const int* ei = (const int*)d_in[1];
  const float* W1 = (const float*)d_in[2];
  const float* b1 = (const float*)d_in[3];
  const float* W2 = (const float*)d_in[4];
  const float* b2 = (const float*)d_in[5];

  const int N = in_sizes[0] / 128;
  const int E = in_sizes[1] / 2;
  const int* src = ei;
  const int* dst = ei + E;
  const int nb = (N + BSPAN - 1) >> BSHIFT;  // # coarse buckets (196 @ N=100K)

  char* p = (char*)d_ws;
  auto take = [&](size_t bytes) -> char* {
    char* q = p;
    p += (bytes + 255) & ~(size_t)255;
    return q;
  };
  int* bins = (int*)take((size_t)NB_MAX * CAP * 4);
  int* tail = (int*)take(NB_MAX * 4);
  int* bbase = (int*)take(NB_MAX * 4);
  int* row_ptr = (int*)take((size_t)(N + 1) * 4);
  int* col = (int*)take((size_t)E * 4);
  float* dinv = (float*)take((size_t)N * 4);
  float* g1 = (float*)take((size_t)N * 64 * 4);
  float* h = (float*)take((size_t)N * 64 * 4);
  float* g2 = (float*)take((size_t)N * 32 * 4);

  hipMemsetAsync(tail, 0, NB_MAX * 4, stream);

  binpass<<<(E + EPBB - 1) / EPBB, BLK, 0, stream>>>(src, dst, E, bins, tail);
  scan256<<<1, BLK, 0, stream>>>(tail, bbase, row_ptr, N, E);
  bucket_sort<<<nb, BLK, 0, stream>>>(bins, tail, bbase, row_ptr, col, dinv, N);

  gemm_kernel<128, 64, 8><<<(N + 31) / 32, BLK, 0, stream>>>(x, W1, dinv, g1, N);
  agg1_kernel<<<(N + 3) / 4, BLK, 0, stream>>>(g1, row_ptr, col, dinv, b1, h, N);
  gemm_kernel<64, 32, 8><<<(N + 63) / 64, BLK, 0, stream>>>(h, W2, dinv, g2, N);
  agg2_kernel<<<(N + 3) / 4, BLK, 0, stream>>>(g2, row_ptr, col, dinv, b2, (float*)d_out, N);
}

// Round 5
// 232.618 us; speedup vs baseline: 2.2254x; 1.1548x over previous
//
#include <hip/hip_runtime.h>
#include <math.h>

constexpr int BLK = 256;
constexpr int NB_MAX = 256;      // max coarse buckets (supports N <= 131072)
constexpr int BSHIFT = 9;        // 512 nodes per bucket
constexpr int BSPAN = 1 << BSHIFT;
constexpr int CAP = 10240;       // per-bucket bin capacity (mean 8192 @ E=1.6M)
constexpr int EPT2 = 16;         // edges per thread in binpass
constexpr int EPBB = BLK * EPT2; // 4096 edges per block

// ---- bf16 helpers (storage-only precision reduction for gather arrays) ----
__device__ __forceinline__ float bf2f(unsigned short u) {
  union { unsigned int i; float f; } v;
  v.i = ((unsigned int)u) << 16;
  return v.f;
}
__device__ __forceinline__ unsigned short f2bf(float f) {
  union { float f; unsigned int i; } v;
  v.f = f;
  unsigned int r = v.i + 0x7FFF + ((v.i >> 16) & 1);  // RNE
  return (unsigned short)(r >> 16);
}

// ---------------- pass 1: coarse binning into block-private chunks ----------------
__global__ void __launch_bounds__(BLK) binpass(const int* __restrict__ src,
                                               const int* __restrict__ dst,
                                               int e, int* __restrict__ bins,
                                               int* __restrict__ tail) {
  __shared__ int lcnt[NB_MAX], gbase[NB_MAX], lcur[NB_MAX];
  const int tid = threadIdx.x;
  lcnt[tid] = 0;
  lcur[tid] = 0;
  __syncthreads();
  const int i0 = blockIdx.x * EPBB;
  int bb[EPT2], pk[EPT2];
#pragma unroll
  for (int k = 0; k < EPT2; k++) {
    int i = i0 + k * BLK + tid;
    if (i < e) {
      int d = dst[i], s = src[i];
      bb[k] = d >> BSHIFT;
      pk[k] = ((d & (BSPAN - 1)) << 23) | s;   // src < 2^23, dlo < 2^9
      atomicAdd(&lcnt[bb[k]], 1);
    } else {
      bb[k] = -1;
    }
  }
  __syncthreads();
  gbase[tid] = atomicAdd(&tail[tid], lcnt[tid]);  // reserve contiguous chunk per bucket
  __syncthreads();
#pragma unroll
  for (int k = 0; k < EPT2; k++) {
    if (bb[k] >= 0) {
      int idx = atomicAdd(&lcur[bb[k]], 1);
      bins[bb[k] * CAP + gbase[bb[k]] + idx] = pk[k];
    }
  }
}

// ---------------- pass 2: exclusive scan of bucket totals ----------------
__global__ void __launch_bounds__(BLK) scan256(const int* __restrict__ tail,
                                               int* __restrict__ bbase,
                                               int* __restrict__ row_ptr,
                                               int n, int e) {
  __shared__ int sd[BLK];
  int v = tail[threadIdx.x];
  sd[threadIdx.x] = v;
  __syncthreads();
  for (int off = 1; off < BLK; off <<= 1) {
    int t = (threadIdx.x >= off) ? sd[threadIdx.x - off] : 0;
    __syncthreads();
    sd[threadIdx.x] += t;
    __syncthreads();
  }
  bbase[threadIdx.x] = sd[threadIdx.x] - v;
  if (threadIdx.x == 0) row_ptr[n] = e;
}

// ---------------- pass 3: per-bucket counting sort (block-private col region) ----------------
__global__ void __launch_bounds__(BLK) bucket_sort(const int* __restrict__ bins,
                                                   const int* __restrict__ tail,
                                                   const int* __restrict__ bbase,
                                                   int* __restrict__ row_ptr,
                                                   int* __restrict__ col,
                                                   float* __restrict__ dinv, int n) {
  __shared__ int hist[BSPAN], lpre[BSPAN], lcur[BSPAN], sd[BLK];
  const int b = blockIdx.x, tid = threadIdx.x;
  const int cnt = tail[b];
  const int base = bbase[b];
  const int node0 = b << BSHIFT;
  const int nNodes = min(BSPAN, n - node0);
  const int* bin = bins + (size_t)b * CAP;

  hist[tid] = 0; hist[tid + BLK] = 0;
  lcur[tid] = 0; lcur[tid + BLK] = 0;
  __syncthreads();
  for (int j = tid; j < cnt; j += BLK) atomicAdd(&hist[(unsigned)bin[j] >> 23], 1);
  __syncthreads();
  // exclusive scan over 512 counters (2 per thread)
  int v0 = hist[2 * tid], v1 = hist[2 * tid + 1], ts = v0 + v1;
  sd[tid] = ts;
  __syncthreads();
  for (int off = 1; off < BLK; off <<= 1) {
    int t = (tid >= off) ? sd[tid - off] : 0;
    __syncthreads();
    sd[tid] += t;
    __syncthreads();
  }
  int ex = sd[tid] - ts;
  lpre[2 * tid] = ex;
  lpre[2 * tid + 1] = ex + v0;
  __syncthreads();
  for (int d = tid; d < nNodes; d += BLK) {
    row_ptr[node0 + d] = base + lpre[d];
    dinv[node0 + d] = rsqrtf((float)hist[d] + 1.0f);
  }
  for (int j = tid; j < cnt; j += BLK) {
    int pkv = bin[j];
    int dlo = (unsigned)pkv >> 23;
    int idx = atomicAdd(&lcur[dlo], 1);
    col[base + lpre[dlo] + idx] = pkv & 0x7FFFFF;
  }
}

// ---------------- dense GEMM: G[n][M] = bf16((X[n][K] @ W[K][M]) * dinv[n]) ----------------
template <int K, int M, int R>
__global__ void __launch_bounds__(BLK) gemm_kernel(const float* __restrict__ X,
                                                   const float* __restrict__ W,
                                                   const float* __restrict__ dinv,
                                                   unsigned short* __restrict__ G, int n) {
  constexpr int GROUPS = BLK / M;
  constexpr int ROWS = GROUPS * R;
  __shared__ float ws[K][M];
  __shared__ float xs[ROWS][K];
  const int tid = threadIdx.x;

  constexpr int WTOT = K * M;
#pragma unroll
  for (int i = tid * 4; i < WTOT; i += BLK * 4) {
    *(float4*)&((float*)ws)[i] = *(const float4*)&W[i];
  }
  const int row0 = blockIdx.x * ROWS;
  constexpr int XTOT = ROWS * K;
#pragma unroll
  for (int i = tid * 4; i < XTOT; i += BLK * 4) {
    int r = i / K, c = i % K;
    int gr = row0 + r;
    if (gr >= n) gr = n - 1;  // clamp (stores are guarded)
    *(float4*)&xs[r][c] = *(const float4*)&X[(size_t)gr * K + c];
  }
  __syncthreads();

  const int col = tid % M;
  const int grp = tid / M;
  float acc[R];
#pragma unroll
  for (int r = 0; r < R; r++) acc[r] = 0.f;

  for (int k = 0; k < K; k += 4) {
    float w0 = ws[k][col], w1 = ws[k + 1][col], w2 = ws[k + 2][col], w3 = ws[k + 3][col];
#pragma unroll
    for (int r = 0; r < R; r++) {
      float4 xv = *(const float4*)&xs[grp * R + r][k];
      acc[r] += xv.x * w0 + xv.y * w1 + xv.z * w2 + xv.w * w3;
    }
  }

#pragma unroll
  for (int r = 0; r < R; r++) {
    int gr = row0 + grp * R + r;
    if (gr < n) G[(size_t)gr * M + col] = f2bf(acc[r] * dinv[gr]);
  }
}

// ---------------- aggregation ----------------
// gs (bf16) holds (X@W)*dinv[row]. out[i] = relu(dinv[i]*(gs[i] + sum_s gs[s]) + b)

// layer 1: 64 channels bf16, one wave per node, lane = channel.
// All batches are 8-wide with clamp+mask: no serial remainder chain.
__global__ void __launch_bounds__(BLK) agg1_kernel(const unsigned short* __restrict__ gs,
                                                   const int* __restrict__ row_ptr,
                                                   const int* __restrict__ col,
                                                   const float* __restrict__ dinv,
                                                   const float* __restrict__ bias,
                                                   float* __restrict__ out, int n) {
  int node = (blockIdx.x * BLK + threadIdx.x) >> 6;
  int lane = threadIdx.x & 63;
  if (node >= n) return;
  int beg = row_ptr[node], end = row_ptr[node + 1];
  float acc = bf2f(gs[(size_t)node * 64 + lane]);  // self-loop (prescaled)
  int e1 = end - 1;
  for (int j = beg; j < end; j += 8) {
    int s[8];
#pragma unroll
    for (int t = 0; t < 8; t++) {
      int jj = j + t;
      s[t] = col[jj <= e1 ? jj : e1];
    }
    float a[8];
#pragma unroll
    for (int t = 0; t < 8; t++) a[t] = bf2f(gs[(size_t)s[t] * 64 + lane]);
#pragma unroll
    for (int t = 0; t < 8; t++) acc += (j + t <= e1) ? a[t] : 0.f;
  }
  float v = acc * dinv[node] + bias[lane];
  out[(size_t)node * 64 + lane] = v > 0.f ? v : 0.f;
}

// layer 2: 32 channels bf16; wave halves process alternate neighbors, 4-wide batches.
__global__ void __launch_bounds__(BLK) agg2_kernel(const unsigned short* __restrict__ gs,
                                                   const int* __restrict__ row_ptr,
                                                   const int* __restrict__ col,
                                                   const float* __restrict__ dinv,
                                                   const float* __restrict__ bias,
                                                   float* __restrict__ out, int n) {
  int node = (blockIdx.x * BLK + threadIdx.x) >> 6;
  int lane = threadIdx.x & 63;
  if (node >= n) return;
  int c = lane & 31, half = lane >> 5;
  float acc = (half == 0) ? bf2f(gs[(size_t)node * 32 + c]) : 0.f;
  int beg = row_ptr[node], end = row_ptr[node + 1];
  int e1 = end - 1;
  for (int j = beg + half; j < end; j += 8) {
    int s[4];
#pragma unroll
    for (int t = 0; t < 4; t++) {
      int jj = j + 2 * t;
      s[t] = col[jj <= e1 ? jj : e1];
    }
    float a[4];
#pragma unroll
    for (int t = 0; t < 4; t++) a[t] = bf2f(gs[(size_t)s[t] * 32 + c]);
#pragma unroll
    for (int t = 0; t < 4; t++) acc += (j + 2 * t <= e1) ? a[t] : 0.f;
  }
  acc += __shfl_xor(acc, 32);
  if (half == 0) {
    float v = acc * dinv[node] + bias[c];
    out[(size_t)node * 32 + c] = v > 0.f ? v : 0.f;
  }
}

// ---------------- launcher ----------------

extern "C" void kernel_launch(void* const* d_in, const int* in_sizes, int n_in,
                              void* d_out, int out_size, void* d_ws, size_t ws_size,
                              hipStream_t stream) {
  const float* x = (const float*)d_in[0];
  const int* ei = (const int*)d_in[1];
  const float* W1 = (const float*)d_in[2];
  const float* b1 = (const float*)d_in[3];
  const float* W2 = (const float*)d_in[4];
  const float* b2 = (const float*)d_in[5];

  const int N = in_sizes[0] / 128;
  const int E = in_sizes[1] / 2;
  const int* src = ei;
  const int* dst = ei + E;
  const int nb = (N + BSPAN - 1) >> BSHIFT;  // # coarse buckets (196 @ N=100K)

  char* p = (char*)d_ws;
  auto take = [&](size_t bytes) -> char* {
    char* q = p;
    p += (bytes + 255) & ~(size_t)255;
    return q;
  };
  int* bins = (int*)take((size_t)NB_MAX * CAP * 4);
  int* tail = (int*)take(NB_MAX * 4);
  int* bbase = (int*)take(NB_MAX * 4);
  int* row_ptr = (int*)take((size_t)(N + 1) * 4);
  int* col = (int*)take((size_t)E * 4);
  float* dinv = (float*)take((size_t)N * 4);
  unsigned short* g1 = (unsigned short*)take((size_t)N * 64 * 2);
  float* h = (float*)take((size_t)N * 64 * 4);
  unsigned short* g2 = (unsigned short*)take((size_t)N * 32 * 2);

  hipMemsetAsync(tail, 0, NB_MAX * 4, stream);

  binpass<<<(E + EPBB - 1) / EPBB, BLK, 0, stream>>>(src, dst, E, bins, tail);
  scan256<<<1, BLK, 0, stream>>>(tail, bbase, row_ptr, N, E);
  bucket_sort<<<nb, BLK, 0, stream>>>(bins, tail, bbase, row_ptr, col, dinv, N);

  gemm_kernel<128, 64, 8><<<(N + 31) / 32, BLK, 0, stream>>>(x, W1, dinv, g1, N);
  agg1_kernel<<<(N + 3) / 4, BLK, 0, stream>>>(g1, row_ptr, col, dinv, b1, h, N);
  gemm_kernel<64, 32, 4><<<(N + 31) / 32, BLK, 0, stream>>>(h, W2, dinv, g2, N);
  agg2_kernel<<<(N + 3) / 4, BLK, 0, stream>>>(g2, row_ptr, col, dinv, b2, (float*)d_out, N);
}

// Round 6
// 230.547 us; speedup vs baseline: 2.2454x; 1.0090x over previous
//
#include <hip/hip_runtime.h>
#include <math.h>

constexpr int BLK = 256;
constexpr int NB_MAX = 256;      // max coarse buckets (supports N <= 131072)
constexpr int BSHIFT = 9;        // 512 nodes per bucket
constexpr int BSPAN = 1 << BSHIFT;
constexpr int CAP = 10240;       // per-bucket bin capacity (mean 8192 @ E=1.6M)
constexpr int EPT2 = 16;         // edges per thread in binpass
constexpr int EPBB = BLK * EPT2; // 4096 edges per block

typedef unsigned short u16;
typedef __attribute__((ext_vector_type(8))) unsigned short ushort8_t;
typedef __attribute__((ext_vector_type(4))) unsigned short ushort4_t;

// ---- bf16 helpers (storage-only precision reduction for gather arrays) ----
__device__ __forceinline__ float bf2f(u16 u) {
  union { unsigned int i; float f; } v;
  v.i = ((unsigned int)u) << 16;
  return v.f;
}
__device__ __forceinline__ u16 f2bf(float f) {
  union { float f; unsigned int i; } v;
  v.f = f;
  unsigned int r = v.i + 0x7FFF + ((v.i >> 16) & 1);  // RNE
  return (u16)(r >> 16);
}

// ---------------- pass 1: coarse binning into block-private chunks ----------------
__global__ void __launch_bounds__(BLK) binpass(const int* __restrict__ src,
                                               const int* __restrict__ dst,
                                               int e, int* __restrict__ bins,
                                               int* __restrict__ tail) {
  __shared__ int lcnt[NB_MAX], gbase[NB_MAX], lcur[NB_MAX];
  const int tid = threadIdx.x;
  lcnt[tid] = 0;
  lcur[tid] = 0;
  __syncthreads();
  const int i0 = blockIdx.x * EPBB;
  int bb[EPT2], pk[EPT2];
#pragma unroll
  for (int k = 0; k < EPT2; k++) {
    int i = i0 + k * BLK + tid;
    if (i < e) {
      int d = dst[i], s = src[i];
      bb[k] = d >> BSHIFT;
      pk[k] = ((d & (BSPAN - 1)) << 23) | s;   // src < 2^23, dlo < 2^9
      atomicAdd(&lcnt[bb[k]], 1);
    } else {
      bb[k] = -1;
    }
  }
  __syncthreads();
  gbase[tid] = atomicAdd(&tail[tid], lcnt[tid]);  // reserve contiguous chunk per bucket
  __syncthreads();
#pragma unroll
  for (int k = 0; k < EPT2; k++) {
    if (bb[k] >= 0) {
      int idx = atomicAdd(&lcur[bb[k]], 1);
      bins[bb[k] * CAP + gbase[bb[k]] + idx] = pk[k];
    }
  }
}

// ---------------- pass 2: exclusive scan of bucket totals ----------------
__global__ void __launch_bounds__(BLK) scan256(const int* __restrict__ tail,
                                               int* __restrict__ bbase,
                                               int* __restrict__ row_ptr,
                                               int n, int e) {
  __shared__ int sd[BLK];
  int v = tail[threadIdx.x];
  sd[threadIdx.x] = v;
  __syncthreads();
  for (int off = 1; off < BLK; off <<= 1) {
    int t = (threadIdx.x >= off) ? sd[threadIdx.x - off] : 0;
    __syncthreads();
    sd[threadIdx.x] += t;
    __syncthreads();
  }
  bbase[threadIdx.x] = sd[threadIdx.x] - v;
  if (threadIdx.x == 0) row_ptr[n] = e;
}

// ---------------- pass 3: per-bucket counting sort (block-private col region) ----------------
__global__ void __launch_bounds__(BLK) bucket_sort(const int* __restrict__ bins,
                                                   const int* __restrict__ tail,
                                                   const int* __restrict__ bbase,
                                                   int* __restrict__ row_ptr,
                                                   int* __restrict__ col,
                                                   float* __restrict__ dinv, int n) {
  __shared__ int hist[BSPAN], lpre[BSPAN], lcur[BSPAN], sd[BLK];
  const int b = blockIdx.x, tid = threadIdx.x;
  const int cnt = tail[b];
  const int base = bbase[b];
  const int node0 = b << BSHIFT;
  const int nNodes = min(BSPAN, n - node0);
  const int* bin = bins + (size_t)b * CAP;

  hist[tid] = 0; hist[tid + BLK] = 0;
  lcur[tid] = 0; lcur[tid + BLK] = 0;
  __syncthreads();
  for (int j = tid; j < cnt; j += BLK) atomicAdd(&hist[(unsigned)bin[j] >> 23], 1);
  __syncthreads();
  // exclusive scan over 512 counters (2 per thread)
  int v0 = hist[2 * tid], v1 = hist[2 * tid + 1], ts = v0 + v1;
  sd[tid] = ts;
  __syncthreads();
  for (int off = 1; off < BLK; off <<= 1) {
    int t = (tid >= off) ? sd[tid - off] : 0;
    __syncthreads();
    sd[tid] += t;
    __syncthreads();
  }
  int ex = sd[tid] - ts;
  lpre[2 * tid] = ex;
  lpre[2 * tid + 1] = ex + v0;
  __syncthreads();
  for (int d = tid; d < nNodes; d += BLK) {
    row_ptr[node0 + d] = base + lpre[d];
    dinv[node0 + d] = rsqrtf((float)hist[d] + 1.0f);
  }
  for (int j = tid; j < cnt; j += BLK) {
    int pkv = bin[j];
    int dlo = (unsigned)pkv >> 23;
    int idx = atomicAdd(&lcur[dlo], 1);
    col[base + lpre[dlo] + idx] = pkv & 0x7FFFFF;
  }
}

// ---------------- dense GEMM: G[n][M] = bf16((X[n][K] @ W[K][M]) * dinv[n]) ----------------
// Register-tiled: 256 threads = 8 col-groups (cg = tid>>5) x 32 row-lanes (rg).
// Each thread: R=8 rows (rg + 32*r) x C=M/8 cols. W transposed in LDS (broadcast
// reads, conflict-free); X staged in K-chunks with stride KSTAGE+2 (float2 reads,
// lane stride 18 words -> 2-way bank alias = free).
template <int K, int M, int KSTAGE>
__global__ void __launch_bounds__(BLK) gemm_rc(const float* __restrict__ X,
                                               const float* __restrict__ W,
                                               const float* __restrict__ dinv,
                                               u16* __restrict__ G, int n) {
  constexpr int C = M / 8;
  constexpr int R = 8;
  constexpr int ROWS = 256;
  constexpr int C4N = KSTAGE / 4;                 // float4 chunks per row per stage
  constexpr int LOAD_IT = ROWS * C4N / BLK;       // float4 loads per thread per stage
  __shared__ float xs[ROWS][KSTAGE + 2];
  __shared__ float wsT[M][K];

  const int tid = threadIdx.x;
  const int row0 = blockIdx.x * ROWS;
  const int cg = tid >> 5;
  const int rg = tid & 31;

  // stage W transposed (one-time, 2-8KB..32KB)
  for (int i = tid; i < K * M; i += BLK) {
    int k = i / M, m = i % M;
    wsT[m][k] = W[i];
  }

  float acc[R][C];
#pragma unroll
  for (int r = 0; r < R; r++)
#pragma unroll
    for (int c = 0; c < C; c++) acc[r][c] = 0.f;

  for (int ks = 0; ks < K; ks += KSTAGE) {
    __syncthreads();  // protect xs from prior-stage readers; covers wsT on iter 0
#pragma unroll
    for (int jj = 0; jj < LOAD_IT; jj++) {
      int f = tid + BLK * jj;
      int r = f / C4N, c4 = f % C4N;
      int gr = row0 + r;
      if (gr >= n) gr = n - 1;  // clamp (stores are guarded)
      float4 v = *(const float4*)&X[(size_t)gr * K + ks + c4 * 4];
      *(float2*)&xs[r][c4 * 4] = make_float2(v.x, v.y);
      *(float2*)&xs[r][c4 * 4 + 2] = make_float2(v.z, v.w);
    }
    __syncthreads();
#pragma unroll
    for (int k4 = 0; k4 < KSTAGE; k4 += 4) {
      float2 xa[R], xb[R];
#pragma unroll
      for (int r = 0; r < R; r++) {
        xa[r] = *(const float2*)&xs[rg + 32 * r][k4];
        xb[r] = *(const float2*)&xs[rg + 32 * r][k4 + 2];
      }
      float4 wv[C];
#pragma unroll
      for (int c = 0; c < C; c++) wv[c] = *(const float4*)&wsT[cg * C + c][ks + k4];
#pragma unroll
      for (int r = 0; r < R; r++)
#pragma unroll
        for (int c = 0; c < C; c++)
          acc[r][c] += xa[r].x * wv[c].x + xa[r].y * wv[c].y +
                       xb[r].x * wv[c].z + xb[r].y * wv[c].w;
    }
  }

#pragma unroll
  for (int r = 0; r < R; r++) {
    int gr = row0 + rg + 32 * r;
    if (gr < n) {
      float s = dinv[gr];
      u16 tmp[C];
#pragma unroll
      for (int c = 0; c < C; c++) tmp[c] = f2bf(acc[r][c] * s);
      if constexpr (C == 8)
        *(ushort8_t*)&G[(size_t)gr * M + cg * C] = *(ushort8_t*)tmp;
      else
        *(ushort4_t*)&G[(size_t)gr * M + cg * C] = *(ushort4_t*)tmp;
    }
  }
}

// ---------------- aggregation ----------------
// gs (bf16) holds (X@W)*dinv[row]. out[i] = relu(dinv[i]*(gs[i] + sum_s gs[s]) + b)

__global__ void __launch_bounds__(BLK) agg1_kernel(const u16* __restrict__ gs,
                                                   const int* __restrict__ row_ptr,
                                                   const int* __restrict__ col,
                                                   const float* __restrict__ dinv,
                                                   const float* __restrict__ bias,
                                                   float* __restrict__ out, int n) {
  int node = (blockIdx.x * BLK + threadIdx.x) >> 6;
  int lane = threadIdx.x & 63;
  if (node >= n) return;
  int beg = row_ptr[node], end = row_ptr[node + 1];
  float acc = bf2f(gs[(size_t)node * 64 + lane]);  // self-loop (prescaled)
  int e1 = end - 1;
  for (int j = beg; j < end; j += 8) {
    int s[8];
#pragma unroll
    for (int t = 0; t < 8; t++) {
      int jj = j + t;
      s[t] = col[jj <= e1 ? jj : e1];
    }
    float a[8];
#pragma unroll
    for (int t = 0; t < 8; t++) a[t] = bf2f(gs[(size_t)s[t] * 64 + lane]);
#pragma unroll
    for (int t = 0; t < 8; t++) acc += (j + t <= e1) ? a[t] : 0.f;
  }
  float v = acc * dinv[node] + bias[lane];
  out[(size_t)node * 64 + lane] = v > 0.f ? v : 0.f;
}

__global__ void __launch_bounds__(BLK) agg2_kernel(const u16* __restrict__ gs,
                                                   const int* __restrict__ row_ptr,
                                                   const int* __restrict__ col,
                                                   const float* __restrict__ dinv,
                                                   const float* __restrict__ bias,
                                                   float* __restrict__ out, int n) {
  int node = (blockIdx.x * BLK + threadIdx.x) >> 6;
  int lane = threadIdx.x & 63;
  if (node >= n) return;
  int c = lane & 31, half = lane >> 5;
  float acc = (half == 0) ? bf2f(gs[(size_t)node * 32 + c]) : 0.f;
  int beg = row_ptr[node], end = row_ptr[node + 1];
  int e1 = end - 1;
  for (int j = beg + half; j < end; j += 8) {
    int s[4];
#pragma unroll
    for (int t = 0; t < 4; t++) {
      int jj = j + 2 * t;
      s[t] = col[jj <= e1 ? jj : e1];
    }
    float a[4];
#pragma unroll
    for (int t = 0; t < 4; t++) a[t] = bf2f(gs[(size_t)s[t] * 32 + c]);
#pragma unroll
    for (int t = 0; t < 4; t++) acc += (j + 2 * t <= e1) ? a[t] : 0.f;
  }
  acc += __shfl_xor(acc, 32);
  if (half == 0) {
    float v = acc * dinv[node] + bias[c];
    out[(size_t)node * 32 + c] = v > 0.f ? v : 0.f;
  }
}

// ---------------- launcher ----------------

extern "C" void kernel_launch(void* const* d_in, const int* in_sizes, int n_in,
                              void* d_out, int out_size, void* d_ws, size_t ws_size,
                              hipStream_t stream) {
  const float* x = (const float*)d_in[0];
  const int* ei = (const int*)d_in[1];
  const float* W1 = (const float*)d_in[2];
  const float* b1 = (const float*)d_in[3];
  const float* W2 = (const float*)d_in[4];
  const float* b2 = (const float*)d_in[5];

  const int N = in_sizes[0] / 128;
  const int E = in_sizes[1] / 2;
  const int* src = ei;
  const int* dst = ei + E;
  const int nb = (N + BSPAN - 1) >> BSHIFT;  // # coarse buckets (196 @ N=100K)

  char* p = (char*)d_ws;
  auto take = [&](size_t bytes) -> char* {
    char* q = p;
    p += (bytes + 255) & ~(size_t)255;
    return q;
  };
  int* bins = (int*)take((size_t)NB_MAX * CAP * 4);
  int* tail = (int*)take(NB_MAX * 4);
  int* bbase = (int*)take(NB_MAX * 4);
  int* row_ptr = (int*)take((size_t)(N + 1) * 4);
  int* col = (int*)take((size_t)E * 4);
  float* dinv = (float*)take((size_t)N * 4);
  u16* g1 = (u16*)take((size_t)N * 64 * 2);
  float* h = (float*)take((size_t)N * 64 * 4);
  u16* g2 = (u16*)take((size_t)N * 32 * 2);

  hipMemsetAsync(tail, 0, NB_MAX * 4, stream);

  binpass<<<(E + EPBB - 1) / EPBB, BLK, 0, stream>>>(src, dst, E, bins, tail);
  scan256<<<1, BLK, 0, stream>>>(tail, bbase, row_ptr, N, E);
  bucket_sort<<<nb, BLK, 0, stream>>>(bins, tail, bbase, row_ptr, col, dinv, N);

  gemm_rc<128, 64, 16><<<(N + 255) / 256, BLK, 0, stream>>>(x, W1, dinv, g1, N);
  agg1_kernel<<<(N + 3) / 4, BLK, 0, stream>>>(g1, row_ptr, col, dinv, b1, h, N);
  gemm_rc<64, 32, 16><<<(N + 255) / 256, BLK, 0, stream>>>(h, W2, dinv, g2, N);
  agg2_kernel<<<(N + 3) / 4, BLK, 0, stream>>>(g2, row_ptr, col, dinv, b2, (float*)d_out, N);
}